// Round 2
// baseline (585.992 us; speedup 1.0000x reference)
//
#include <hip/hip_runtime.h>
#include <cstdint>
#include <cstddef>

#define N 4096
#define D 300
#define INV_T 20.0f
#define SK_ITERS 10

// ---------------- generic zero-fill ----------------
__global__ void zero_u32(unsigned int* __restrict__ p, int n) {
  int i = blockIdx.x * 256 + threadIdx.x;
  int stride = gridDim.x * 256;
  for (; i < n; i += stride) p[i] = 0u;
}

// ---------------- MLP GEMM: C = act(A @ B + bias), A[N,300] B[300,300] ----------------
__global__ __launch_bounds__(320) void mlp_gemm(const float* __restrict__ A,
                                                const float* __restrict__ B,
                                                const float* __restrict__ bias,
                                                float* __restrict__ C, int relu) {
  __shared__ __align__(16) float As[8][300];
  int r0 = blockIdx.x * 8;
  for (int idx = threadIdx.x; idx < 8 * 300; idx += 320) {
    int r = idx / 300, k = idx - r * 300;
    As[r][k] = A[(size_t)(r0 + r) * D + k];
  }
  __syncthreads();
  int c = threadIdx.x;
  if (c < D) {
    float acc[8] = {0, 0, 0, 0, 0, 0, 0, 0};
    for (int k = 0; k < D; k += 4) {
      float b0 = B[(size_t)(k + 0) * D + c];
      float b1 = B[(size_t)(k + 1) * D + c];
      float b2 = B[(size_t)(k + 2) * D + c];
      float b3 = B[(size_t)(k + 3) * D + c];
#pragma unroll
      for (int r = 0; r < 8; ++r) {
        const float4 a4 = *reinterpret_cast<const float4*>(&As[r][k]);
        acc[r] += a4.x * b0 + a4.y * b1 + a4.z * b2 + a4.w * b3;
      }
    }
#pragma unroll
    for (int r = 0; r < 8; ++r) {
      float o = acc[r] + bias[c];
      if (relu) o = fmaxf(o, 0.0f);
      C[(size_t)(r0 + r) * D + c] = o;
    }
  }
}

// ---------------- row L2 normalize (in-place safe): f = out / max(||out||,1e-12) ------
__global__ __launch_bounds__(64) void normalize_rows(const float* __restrict__ in,
                                                     float* __restrict__ out) {
  int row = blockIdx.x;
  const float* r = in + (size_t)row * D;
  float ss = 0.0f;
  for (int c = threadIdx.x; c < D; c += 64) {
    float v = r[c];
    ss += v * v;
  }
  for (int o = 32; o > 0; o >>= 1) ss += __shfl_down(ss, o);
  ss = __shfl(ss, 0);
  float inv = 1.0f / fmaxf(sqrtf(ss), 1e-12f);
  float* wdst = out + (size_t)row * D;
  for (int c = threadIdx.x; c < D; c += 64) wdst[c] = r[c] * inv;
}

// ---------------- logits = (f @ f^T) * INV_T, [N,N] f32 ----------------
#define BK 25
__global__ __launch_bounds__(256) void logits_gemm(const float* __restrict__ f,
                                                   float* __restrict__ logits) {
  __shared__ __align__(16) float As[BK][68];
  __shared__ __align__(16) float Bs[BK][68];
  int bi = blockIdx.y, bj = blockIdx.x;
  int tx = threadIdx.x & 15, ty = threadIdx.x >> 4;
  float acc[4][4] = {};
  int row0 = bi * 64, col0 = bj * 64;
  for (int k0 = 0; k0 < D; k0 += BK) {
    for (int idx = threadIdx.x; idx < 64 * BK; idx += 256) {
      int r = idx / BK, k = idx - r * BK;
      As[k][r] = f[(size_t)(row0 + r) * D + k0 + k];
      Bs[k][r] = f[(size_t)(col0 + r) * D + k0 + k];
    }
    __syncthreads();
#pragma unroll
    for (int kk = 0; kk < BK; ++kk) {
      float4 a4 = *reinterpret_cast<const float4*>(&As[kk][ty * 4]);
      float4 b4 = *reinterpret_cast<const float4*>(&Bs[kk][tx * 4]);
      float a[4] = {a4.x, a4.y, a4.z, a4.w};
      float b[4] = {b4.x, b4.y, b4.z, b4.w};
#pragma unroll
      for (int m = 0; m < 4; ++m)
#pragma unroll
        for (int n = 0; n < 4; ++n) acc[m][n] += a[m] * b[n];
    }
    __syncthreads();
  }
#pragma unroll
  for (int m = 0; m < 4; ++m) {
    float4 o = make_float4(acc[m][0] * INV_T, acc[m][1] * INV_T,
                           acc[m][2] * INV_T, acc[m][3] * INV_T);
    *reinterpret_cast<float4*>(
        &logits[(size_t)(row0 + ty * 4 + m) * N + col0 + tx * 4]) = o;
  }
}

// ---------------- one Sinkhorn half-step: vout = 1 / (K @ vin); K = exp(logits) -------
__global__ __launch_bounds__(256) void sk_pass(const float* __restrict__ logits,
                                               const float* __restrict__ vin,
                                               float* __restrict__ vout,
                                               float* __restrict__ lse, int store_lse) {
  __shared__ float sbuf[4];
  int row = blockIdx.x;
  const float4* lr = reinterpret_cast<const float4*>(logits + (size_t)row * N);
  const float4* vr = reinterpret_cast<const float4*>(vin);
  float s = 0.0f;
  for (int idx = threadIdx.x; idx < N / 4; idx += 256) {
    float4 l = lr[idx];
    float4 v = vr[idx];
    s += __expf(l.x) * v.x + __expf(l.y) * v.y + __expf(l.z) * v.z + __expf(l.w) * v.w;
  }
  for (int o = 32; o > 0; o >>= 1) s += __shfl_down(s, o);
  int lane = threadIdx.x & 63, wid = threadIdx.x >> 6;
  if (lane == 0) sbuf[wid] = s;
  __syncthreads();
  if (threadIdx.x == 0) {
    float tot = sbuf[0] + sbuf[1] + sbuf[2] + sbuf[3];
    vout[row] = 1.0f / tot;
    if (store_lse) lse[row] = logf(tot);
  }
}

// ------- loss1 row pass: term1[i] = u_i * sum_j exp(l_ij) v_j (l_ij - lse_i) -------
__global__ __launch_bounds__(256) void loss1_pass(const float* __restrict__ logits,
                                                  const float* __restrict__ u,
                                                  const float* __restrict__ v,
                                                  const float* __restrict__ lse,
                                                  double* __restrict__ term1) {
  __shared__ float sbuf[4];
  int row = blockIdx.x;
  float L = lse[row];
  const float4* lr = reinterpret_cast<const float4*>(logits + (size_t)row * N);
  const float4* vr = reinterpret_cast<const float4*>(v);
  float s = 0.0f;
  for (int idx = threadIdx.x; idx < N / 4; idx += 256) {
    float4 l = lr[idx];
    float4 vv = vr[idx];
    s += __expf(l.x) * vv.x * (l.x - L) + __expf(l.y) * vv.y * (l.y - L) +
         __expf(l.z) * vv.z * (l.z - L) + __expf(l.w) * vv.w * (l.w - L);
  }
  for (int o = 32; o > 0; o >>= 1) s += __shfl_down(s, o);
  int lane = threadIdx.x & 63, wid = threadIdx.x >> 6;
  if (lane == 0) sbuf[wid] = s;
  __syncthreads();
  if (threadIdx.x == 0) {
    float tot = sbuf[0] + sbuf[1] + sbuf[2] + sbuf[3];
    term1[row] = (double)u[row] * (double)tot;
  }
}

__global__ void init_ones(float* v) {
  int i = blockIdx.x * 256 + threadIdx.x;
  if (i < N) v[i] = 1.0f;
}

// ---------------- adjacency bitmask build + degree count (edge_index is int32) --------
__global__ void build_adj(const int* __restrict__ ei, int E,
                          unsigned int* __restrict__ adjmask, int* __restrict__ deg) {
  int t = blockIdx.x * 256 + threadIdx.x;
  if (t < E) {
    int s = ei[t] & (N - 1), d = ei[E + t] & (N - 1);
    atomicOr(&adjmask[(size_t)s * 128 + (d >> 5)], 1u << (d & 31));
    atomicAdd(&deg[s], 1);
  }
  if (t < N) atomicOr(&adjmask[(size_t)t * 128 + (t >> 5)], 1u << (t & 31));
}

// ---------------- exclusive scan of degrees (4096, single block) ----------------
__global__ __launch_bounds__(1024) void scan_deg(const int* __restrict__ deg,
                                                 int* __restrict__ offs,
                                                 int* __restrict__ cursor) {
  __shared__ int part[1024];
  int tid = threadIdx.x;
  int base = tid * 4;
  int l0 = deg[base + 0], l1 = deg[base + 1], l2 = deg[base + 2], l3 = deg[base + 3];
  part[tid] = l0 + l1 + l2 + l3;
  __syncthreads();
  for (int d = 1; d < 1024; d <<= 1) {
    int v = (tid >= d) ? part[tid - d] : 0;
    __syncthreads();
    part[tid] += v;
    __syncthreads();
  }
  int run = (tid > 0) ? part[tid - 1] : 0;
  offs[base + 0] = run; cursor[base + 0] = run; run += l0;
  offs[base + 1] = run; cursor[base + 1] = run; run += l1;
  offs[base + 2] = run; cursor[base + 2] = run; run += l2;
  offs[base + 3] = run; cursor[base + 3] = run;
}

__global__ void scatter_edges(const int* __restrict__ ei, int E,
                              int* __restrict__ cursor, int* __restrict__ neigh) {
  int t = blockIdx.x * 256 + threadIdx.x;
  if (t < E) {
    int s = ei[t] & (N - 1), d = ei[E + t] & (N - 1);
    int slot = atomicAdd(&cursor[s], 1);
    neigh[slot] = d;
  }
}

// ---------------- adj2 row = OR of adj rows {i} ∪ N(i); also column counts ----------
__global__ __launch_bounds__(128) void adj2_kernel(const unsigned int* __restrict__ adjmask,
                                                   const int* __restrict__ offs,
                                                   const int* __restrict__ deg,
                                                   const int* __restrict__ neigh,
                                                   unsigned int* __restrict__ adj2,
                                                   int* __restrict__ colcount) {
  int i = blockIdx.x, w = threadIdx.x;
  unsigned int acc = adjmask[(size_t)i * 128 + w];
  int o = offs[i], dg = deg[i];
  for (int n = 0; n < dg; ++n) {
    int k = neigh[o + n];
    acc |= adjmask[(size_t)k * 128 + w];
  }
  adj2[(size_t)i * 128 + w] = acc;
  unsigned int m = acc;
  while (m) {
    int b = __ffs(m) - 1;
    m &= m - 1;
    atomicAdd(&colcount[w * 32 + b], 1);
  }
}

// ------- loss2 row pass: term2[i] = sum_{j in adj2_i} (l_ij - lse_i)/colcount_j -------
__global__ __launch_bounds__(128) void loss2_kernel(const unsigned int* __restrict__ adj2,
                                                    const int* __restrict__ colcount,
                                                    const float* __restrict__ logits,
                                                    const float* __restrict__ lse,
                                                    double* __restrict__ term2) {
  __shared__ float sb[2], sb2[2];
  int i = blockIdx.x, w = threadIdx.x;
  unsigned int m = adj2[(size_t)i * 128 + w];
  const float* lrow = logits + (size_t)i * N;
  float s = 0.0f, sc = 0.0f;
  while (m) {
    int b = __ffs(m) - 1;
    m &= m - 1;
    int j = w * 32 + b;
    float ic = 1.0f / (float)colcount[j];
    s += ic * lrow[j];
    sc += ic;
  }
  for (int o = 32; o > 0; o >>= 1) {
    s += __shfl_down(s, o);
    sc += __shfl_down(sc, o);
  }
  int lane = w & 63, wid = w >> 6;
  if (lane == 0) { sb[wid] = s; sb2[wid] = sc; }
  __syncthreads();
  if (w == 0)
    term2[i] = (double)(sb[0] + sb[1]) - (double)lse[i] * (double)(sb2[0] + sb2[1]);
}

// ---------------- final: loss = -(sum term1 + sum term2) / N ----------------
__global__ __launch_bounds__(256) void final_reduce(const double* __restrict__ term1,
                                                    const double* __restrict__ term2,
                                                    float* __restrict__ out) {
  __shared__ double sb[4];
  double s = 0.0;
  for (int i = threadIdx.x; i < N; i += 256) s += term1[i] + term2[i];
  for (int o = 32; o > 0; o >>= 1) s += __shfl_down(s, o);
  int lane = threadIdx.x & 63, wid = threadIdx.x >> 6;
  if (lane == 0) sb[wid] = s;
  __syncthreads();
  if (threadIdx.x == 0) out[0] = (float)(-(sb[0] + sb[1] + sb[2] + sb[3]) / (double)N);
}

extern "C" void kernel_launch(void* const* d_in, const int* in_sizes, int n_in,
                              void* d_out, int out_size, void* d_ws, size_t ws_size,
                              hipStream_t stream) {
  const float* x  = (const float*)d_in[0];
  const float* W1 = (const float*)d_in[1];
  const float* b1 = (const float*)d_in[2];
  const float* W2 = (const float*)d_in[3];
  const float* b2 = (const float*)d_in[4];
  const int* ei = (const int*)d_in[5];   // harness delivers integer inputs as int32
  int E = in_sizes[5] / 2;
  float* outp = (float*)d_out;

  char* w = (char*)d_ws;
  float* logits = (float*)w;  w += (size_t)N * N * 4;
  float* h      = (float*)w;  w += (size_t)N * D * 4;
  float* o2     = (float*)w;  w += (size_t)N * D * 4;
  float* vecA   = (float*)w;  w += 16384;
  float* vecB   = (float*)w;  w += 16384;
  float* lse    = (float*)w;  w += 16384;
  double* term1 = (double*)w; w += 32768;
  double* term2 = (double*)w; w += 32768;
  // contiguous zero-init region: adjmask | colcount | deg
  unsigned int* adjmask = (unsigned int*)w; w += (size_t)N * 128 * 4;
  int* colcount = (int*)w;    w += 16384;
  int* deg      = (int*)w;    w += 16384;
  int zcount = N * 128 + 4096 + 4096;
  unsigned int* adj2 = (unsigned int*)w; w += (size_t)N * 128 * 4;
  int* offs   = (int*)w;      w += 16384;
  int* cursor = (int*)w;      w += 16384;
  int* neigh  = (int*)w;      w += (size_t)E * 4;

  zero_u32<<<512, 256, 0, stream>>>(adjmask, zcount);

  mlp_gemm<<<N / 8, 320, 0, stream>>>(x, W1, b1, h, 1);
  mlp_gemm<<<N / 8, 320, 0, stream>>>(h, W2, b2, o2, 0);
  normalize_rows<<<N, 64, 0, stream>>>(o2, o2);   // in-place; f == o2
  const float* f = o2;
  dim3 g(64, 64);
  logits_gemm<<<g, 256, 0, stream>>>(f, logits);
  init_ones<<<(N + 255) / 256, 256, 0, stream>>>(vecA);

  int gmax = (E > N ? E : N);
  build_adj<<<(gmax + 255) / 256, 256, 0, stream>>>(ei, E, adjmask, deg);
  scan_deg<<<1, 1024, 0, stream>>>(deg, offs, cursor);
  scatter_edges<<<(E + 255) / 256, 256, 0, stream>>>(ei, E, cursor, neigh);

  for (int it = 0; it < SK_ITERS; ++it) {
    sk_pass<<<N, 256, 0, stream>>>(logits, vecA, vecB, lse, it == 0 ? 1 : 0);
    sk_pass<<<N, 256, 0, stream>>>(logits, vecB, vecA, lse, 0);
  }
  loss1_pass<<<N, 256, 0, stream>>>(logits, vecB, vecA, lse, term1);

  adj2_kernel<<<N, 128, 0, stream>>>(adjmask, offs, deg, neigh, adj2, colcount);
  loss2_kernel<<<N, 128, 0, stream>>>(adj2, colcount, logits, lse, term2);

  final_reduce<<<1, 256, 0, stream>>>(term1, term2, outp);
}

// Round 4
// 461.223 us; speedup vs baseline: 1.2705x; 1.2705x over previous
//
#include <hip/hip_runtime.h>
#include <cstdint>
#include <cstddef>

#define N 4096
#define D 300
#define KP 320          // K padded to multiple of 32 for MFMA
#define INV_T 20.0f
#define SK_ITERS 10

typedef __attribute__((ext_vector_type(8))) short bf16x8;
typedef __attribute__((ext_vector_type(4))) float f32x4;
typedef __attribute__((ext_vector_type(8))) unsigned short ushort8;

// ---------------- generic zero-fill ----------------
__global__ void zero_u32(unsigned int* __restrict__ p, int n) {
  int i = blockIdx.x * 256 + threadIdx.x;
  int stride = gridDim.x * 256;
  for (; i < n; i += stride) p[i] = 0u;
}

// ---------------- MLP GEMM: C = act(A @ B + bias), A[N,300] B[300,300] ----------------
__global__ __launch_bounds__(320) void mlp_gemm(const float* __restrict__ A,
                                                const float* __restrict__ B,
                                                const float* __restrict__ bias,
                                                float* __restrict__ C, int relu) {
  __shared__ __align__(16) float As[8][300];
  int r0 = blockIdx.x * 8;
  for (int idx = threadIdx.x; idx < 8 * 300; idx += 320) {
    int r = idx / 300, k = idx - r * 300;
    As[r][k] = A[(size_t)(r0 + r) * D + k];
  }
  __syncthreads();
  int c = threadIdx.x;
  if (c < D) {
    float acc[8] = {0, 0, 0, 0, 0, 0, 0, 0};
    for (int k = 0; k < D; k += 4) {
      float b0 = B[(size_t)(k + 0) * D + c];
      float b1 = B[(size_t)(k + 1) * D + c];
      float b2 = B[(size_t)(k + 2) * D + c];
      float b3 = B[(size_t)(k + 3) * D + c];
#pragma unroll
      for (int r = 0; r < 8; ++r) {
        const float4 a4 = *reinterpret_cast<const float4*>(&As[r][k]);
        acc[r] += a4.x * b0 + a4.y * b1 + a4.z * b2 + a4.w * b3;
      }
    }
#pragma unroll
    for (int r = 0; r < 8; ++r) {
      float o = acc[r] + bias[c];
      if (relu) o = fmaxf(o, 0.0f);
      C[(size_t)(r0 + r) * D + c] = o;
    }
  }
}

// ------- row L2 normalize + split into bf16 hi/lo (K padded to 320 with zeros) -------
__device__ inline unsigned short bf16_rne(float v) {
  unsigned int u = __float_as_uint(v);
  unsigned int r = u + 0x7fffu + ((u >> 16) & 1u);
  return (unsigned short)(r >> 16);
}

__global__ __launch_bounds__(64) void normalize_split(const float* __restrict__ in,
                                                      unsigned short* __restrict__ fhi,
                                                      unsigned short* __restrict__ flo) {
  int row = blockIdx.x;
  const float* r = in + (size_t)row * D;
  float ss = 0.0f;
  for (int c = threadIdx.x; c < D; c += 64) {
    float v = r[c];
    ss += v * v;
  }
  for (int o = 32; o > 0; o >>= 1) ss += __shfl_down(ss, o);
  ss = __shfl(ss, 0);
  float inv = 1.0f / fmaxf(sqrtf(ss), 1e-12f);
  for (int c = threadIdx.x; c < KP; c += 64) {
    float v = (c < D) ? r[c] * inv : 0.0f;
    unsigned short h = bf16_rne(v);
    float hf = __uint_as_float((unsigned int)h << 16);
    unsigned short lo = bf16_rne(v - hf);
    fhi[(size_t)row * KP + c] = h;
    flo[(size_t)row * KP + c] = lo;
  }
}

// ------- logits = (f @ f^T) * INV_T via split-bf16 MFMA, symmetric upper blocks -------
__global__ __launch_bounds__(256) void logits_mfma(const unsigned short* __restrict__ fhi,
                                                   const unsigned short* __restrict__ flo,
                                                   float* __restrict__ logits) {
  __shared__ unsigned short smem[4 * 128 * 32];  // Ahi | Alo | Bhi | Blo, each [128][32]
  // triangular block decode (32 block-rows)
  int id = blockIdx.x;
  int bi = 0;
  while (id >= 32 - bi) { id -= 32 - bi; ++bi; }
  int bj = bi + id;
  int row0 = bi * 128, col0 = bj * 128;
  int tid = threadIdx.x;
  int w = tid >> 6, l = tid & 63;
  int wr = w >> 1, wc = w & 1;
  f32x4 acc[4][4] = {};

  for (int k0 = 0; k0 < KP; k0 += 32) {
    // stage 32KB: 2048 chunks of 16B; thread handles 8 chunks
    ushort8 stg[8];
#pragma unroll
    for (int t = 0; t < 8; ++t) {
      int c = t * 256 + tid;
      int b = c >> 9, i = c & 511, row = i >> 2, k16 = i & 3;
      const unsigned short* base = (b & 1) ? flo : fhi;
      int blk = (b < 2) ? row0 : col0;
      stg[t] = *reinterpret_cast<const ushort8*>(
          &base[(size_t)(blk + row) * KP + k0 + k16 * 8]);
    }
    __syncthreads();  // previous iteration's readers done before overwrite
#pragma unroll
    for (int t = 0; t < 8; ++t) {
      int c = t * 256 + tid;
      *reinterpret_cast<ushort8*>(&smem[c * 8]) = stg[t];
    }
    __syncthreads();

    bf16x8 ah[4], al[4], bh[4], bl[4];
#pragma unroll
    for (int m = 0; m < 4; ++m) {
      int off = (wr * 64 + m * 16 + (l & 15)) * 32 + (l >> 4) * 8;
      ah[m] = *reinterpret_cast<const bf16x8*>(&smem[0 * 4096 + off]);
      al[m] = *reinterpret_cast<const bf16x8*>(&smem[1 * 4096 + off]);
    }
#pragma unroll
    for (int n = 0; n < 4; ++n) {
      int off = (wc * 64 + n * 16 + (l & 15)) * 32 + (l >> 4) * 8;
      bh[n] = *reinterpret_cast<const bf16x8*>(&smem[2 * 4096 + off]);
      bl[n] = *reinterpret_cast<const bf16x8*>(&smem[3 * 4096 + off]);
    }
#pragma unroll
    for (int m = 0; m < 4; ++m)
#pragma unroll
      for (int n = 0; n < 4; ++n) {
        acc[m][n] = __builtin_amdgcn_mfma_f32_16x16x32_bf16(ah[m], bh[n], acc[m][n], 0, 0, 0);
        acc[m][n] = __builtin_amdgcn_mfma_f32_16x16x32_bf16(ah[m], bl[n], acc[m][n], 0, 0, 0);
        acc[m][n] = __builtin_amdgcn_mfma_f32_16x16x32_bf16(al[m], bh[n], acc[m][n], 0, 0, 0);
      }
  }

  // epilogue: C/D layout col=lane&15, row=(lane>>4)*4+reg
  int rb = row0 + wr * 64, cb = col0 + wc * 64;
  int rsub = (l >> 4) * 4, csub = l & 15;
#pragma unroll
  for (int m = 0; m < 4; ++m) {
#pragma unroll
    for (int n = 0; n < 4; ++n) {
      int col = cb + n * 16 + csub;
#pragma unroll
      for (int j = 0; j < 4; ++j) {
        logits[(size_t)(rb + m * 16 + rsub + j) * N + col] = acc[m][n][j] * INV_T;
      }
    }
  }
  if (bi != bj) {  // mirror store: logits[c][r] = logits[r][c]
#pragma unroll
    for (int m = 0; m < 4; ++m) {
      int r2 = rb + m * 16 + rsub;
#pragma unroll
      for (int n = 0; n < 4; ++n) {
        int c2 = cb + n * 16 + csub;
        float4 o = make_float4(acc[m][n][0] * INV_T, acc[m][n][1] * INV_T,
                               acc[m][n][2] * INV_T, acc[m][n][3] * INV_T);
        *reinterpret_cast<float4*>(&logits[(size_t)c2 * N + r2]) = o;
      }
    }
  }
}

// ---------------- one Sinkhorn half-step: vout = 1 / (K @ vin); K = exp(logits) -------
__global__ __launch_bounds__(256) void sk_pass(const float* __restrict__ logits,
                                               const float* __restrict__ vin,
                                               float* __restrict__ vout,
                                               float* __restrict__ lse, int store_lse) {
  __shared__ float sbuf[4];
  int row = blockIdx.x;
  const float4* lr = reinterpret_cast<const float4*>(logits + (size_t)row * N);
  const float4* vr = reinterpret_cast<const float4*>(vin);
  float s = 0.0f;
  for (int idx = threadIdx.x; idx < N / 4; idx += 256) {
    float4 l = lr[idx];
    float4 v = vr[idx];
    s += __expf(l.x) * v.x + __expf(l.y) * v.y + __expf(l.z) * v.z + __expf(l.w) * v.w;
  }
  for (int o = 32; o > 0; o >>= 1) s += __shfl_down(s, o);
  int lane = threadIdx.x & 63, wid = threadIdx.x >> 6;
  if (lane == 0) sbuf[wid] = s;
  __syncthreads();
  if (threadIdx.x == 0) {
    float tot = sbuf[0] + sbuf[1] + sbuf[2] + sbuf[3];
    vout[row] = 1.0f / tot;
    if (store_lse) lse[row] = logf(tot);
  }
}

// ------- loss1 row pass: term1[i] = u_i * sum_j exp(l_ij) v_j (l_ij - lse_i) -------
__global__ __launch_bounds__(256) void loss1_pass(const float* __restrict__ logits,
                                                  const float* __restrict__ u,
                                                  const float* __restrict__ v,
                                                  const float* __restrict__ lse,
                                                  double* __restrict__ term1) {
  __shared__ float sbuf[4];
  int row = blockIdx.x;
  float L = lse[row];
  const float4* lr = reinterpret_cast<const float4*>(logits + (size_t)row * N);
  const float4* vr = reinterpret_cast<const float4*>(v);
  float s = 0.0f;
  for (int idx = threadIdx.x; idx < N / 4; idx += 256) {
    float4 l = lr[idx];
    float4 vv = vr[idx];
    s += __expf(l.x) * vv.x * (l.x - L) + __expf(l.y) * vv.y * (l.y - L) +
         __expf(l.z) * vv.z * (l.z - L) + __expf(l.w) * vv.w * (l.w - L);
  }
  for (int o = 32; o > 0; o >>= 1) s += __shfl_down(s, o);
  int lane = threadIdx.x & 63, wid = threadIdx.x >> 6;
  if (lane == 0) sbuf[wid] = s;
  __syncthreads();
  if (threadIdx.x == 0) {
    float tot = sbuf[0] + sbuf[1] + sbuf[2] + sbuf[3];
    term1[row] = (double)u[row] * (double)tot;
  }
}

__global__ void init_ones(float* v) {
  int i = blockIdx.x * 256 + threadIdx.x;
  if (i < N) v[i] = 1.0f;
}

// ---------------- adjacency bitmask build + degree count (edge_index is int32) --------
__global__ void build_adj(const int* __restrict__ ei, int E,
                          unsigned int* __restrict__ adjmask, int* __restrict__ deg) {
  int t = blockIdx.x * 256 + threadIdx.x;
  if (t < E) {
    int s = ei[t] & (N - 1), d = ei[E + t] & (N - 1);
    atomicOr(&adjmask[(size_t)s * 128 + (d >> 5)], 1u << (d & 31));
    atomicAdd(&deg[s], 1);
  }
  if (t < N) atomicOr(&adjmask[(size_t)t * 128 + (t >> 5)], 1u << (t & 31));
}

// ---------------- exclusive scan of degrees (4096, single block) ----------------
__global__ __launch_bounds__(1024) void scan_deg(const int* __restrict__ deg,
                                                 int* __restrict__ offs,
                                                 int* __restrict__ cursor) {
  __shared__ int part[1024];
  int tid = threadIdx.x;
  int base = tid * 4;
  int l0 = deg[base + 0], l1 = deg[base + 1], l2 = deg[base + 2], l3 = deg[base + 3];
  part[tid] = l0 + l1 + l2 + l3;
  __syncthreads();
  for (int d = 1; d < 1024; d <<= 1) {
    int v = (tid >= d) ? part[tid - d] : 0;
    __syncthreads();
    part[tid] += v;
    __syncthreads();
  }
  int run = (tid > 0) ? part[tid - 1] : 0;
  offs[base + 0] = run; cursor[base + 0] = run; run += l0;
  offs[base + 1] = run; cursor[base + 1] = run; run += l1;
  offs[base + 2] = run; cursor[base + 2] = run; run += l2;
  offs[base + 3] = run; cursor[base + 3] = run;
}

__global__ void scatter_edges(const int* __restrict__ ei, int E,
                              int* __restrict__ cursor, int* __restrict__ neigh) {
  int t = blockIdx.x * 256 + threadIdx.x;
  if (t < E) {
    int s = ei[t] & (N - 1), d = ei[E + t] & (N - 1);
    int slot = atomicAdd(&cursor[s], 1);
    neigh[slot] = d;
  }
}

// ---------------- adj2 row = OR of adj rows {i} ∪ N(i); also column counts ----------
__global__ __launch_bounds__(128) void adj2_kernel(const unsigned int* __restrict__ adjmask,
                                                   const int* __restrict__ offs,
                                                   const int* __restrict__ deg,
                                                   const int* __restrict__ neigh,
                                                   unsigned int* __restrict__ adj2,
                                                   int* __restrict__ colcount) {
  int i = blockIdx.x, w = threadIdx.x;
  unsigned int acc = adjmask[(size_t)i * 128 + w];
  int o = offs[i], dg = deg[i];
  for (int n = 0; n < dg; ++n) {
    int k = neigh[o + n];
    acc |= adjmask[(size_t)k * 128 + w];
  }
  adj2[(size_t)i * 128 + w] = acc;
  unsigned int m = acc;
  while (m) {
    int b = __ffs(m) - 1;
    m &= m - 1;
    atomicAdd(&colcount[w * 32 + b], 1);
  }
}

// ------- loss2 row pass: term2[i] = sum_{j in adj2_i} (l_ij - lse_i)/colcount_j -------
__global__ __launch_bounds__(128) void loss2_kernel(const unsigned int* __restrict__ adj2,
                                                    const int* __restrict__ colcount,
                                                    const float* __restrict__ logits,
                                                    const float* __restrict__ lse,
                                                    double* __restrict__ term2) {
  __shared__ float sb[2], sb2[2];
  int i = blockIdx.x, w = threadIdx.x;
  unsigned int m = adj2[(size_t)i * 128 + w];
  const float* lrow = logits + (size_t)i * N;
  float s = 0.0f, sc = 0.0f;
  while (m) {
    int b = __ffs(m) - 1;
    m &= m - 1;
    int j = w * 32 + b;
    float ic = 1.0f / (float)colcount[j];
    s += ic * lrow[j];
    sc += ic;
  }
  for (int o = 32; o > 0; o >>= 1) {
    s += __shfl_down(s, o);
    sc += __shfl_down(sc, o);
  }
  int lane = w & 63, wid = w >> 6;
  if (lane == 0) { sb[wid] = s; sb2[wid] = sc; }
  __syncthreads();
  if (w == 0)
    term2[i] = (double)(sb[0] + sb[1]) - (double)lse[i] * (double)(sb2[0] + sb2[1]);
}

// ---------------- final: loss = -(sum term1 + sum term2) / N ----------------
__global__ __launch_bounds__(256) void final_reduce(const double* __restrict__ term1,
                                                    const double* __restrict__ term2,
                                                    float* __restrict__ out) {
  __shared__ double sb[4];
  double s = 0.0;
  for (int i = threadIdx.x; i < N; i += 256) s += term1[i] + term2[i];
  for (int o = 32; o > 0; o >>= 1) s += __shfl_down(s, o);
  int lane = threadIdx.x & 63, wid = threadIdx.x >> 6;
  if (lane == 0) sb[wid] = s;
  __syncthreads();
  if (threadIdx.x == 0) out[0] = (float)(-(sb[0] + sb[1] + sb[2] + sb[3]) / (double)N);
}

extern "C" void kernel_launch(void* const* d_in, const int* in_sizes, int n_in,
                              void* d_out, int out_size, void* d_ws, size_t ws_size,
                              hipStream_t stream) {
  const float* x  = (const float*)d_in[0];
  const float* W1 = (const float*)d_in[1];
  const float* b1 = (const float*)d_in[2];
  const float* W2 = (const float*)d_in[3];
  const float* b2 = (const float*)d_in[4];
  const int* ei = (const int*)d_in[5];   // harness delivers integer inputs as int32
  int E = in_sizes[5] / 2;
  float* outp = (float*)d_out;

  char* w = (char*)d_ws;
  float* logits = (float*)w;  w += (size_t)N * N * 4;
  float* h      = (float*)w;  w += (size_t)N * D * 4;
  float* o2     = (float*)w;  w += (size_t)N * D * 4;
  unsigned short* fhi = (unsigned short*)w; w += (size_t)N * KP * 2;
  unsigned short* flo = (unsigned short*)w; w += (size_t)N * KP * 2;
  float* vecA   = (float*)w;  w += 16384;
  float* vecB   = (float*)w;  w += 16384;
  float* lse    = (float*)w;  w += 16384;
  double* term1 = (double*)w; w += 32768;
  double* term2 = (double*)w; w += 32768;
  // contiguous zero-init region: adjmask | colcount | deg
  unsigned int* adjmask = (unsigned int*)w; w += (size_t)N * 128 * 4;
  int* colcount = (int*)w;    w += 16384;
  int* deg      = (int*)w;    w += 16384;
  int zcount = N * 128 + 4096 + 4096;
  unsigned int* adj2 = (unsigned int*)w; w += (size_t)N * 128 * 4;
  int* offs   = (int*)w;      w += 16384;
  int* cursor = (int*)w;      w += 16384;
  int* neigh  = (int*)w;      w += (size_t)E * 4;

  zero_u32<<<512, 256, 0, stream>>>(adjmask, zcount);

  mlp_gemm<<<N / 8, 320, 0, stream>>>(x, W1, b1, h, 1);
  mlp_gemm<<<N / 8, 320, 0, stream>>>(h, W2, b2, o2, 0);
  normalize_split<<<N, 64, 0, stream>>>(o2, fhi, flo);
  logits_mfma<<<528, 256, 0, stream>>>(fhi, flo, logits);
  init_ones<<<(N + 255) / 256, 256, 0, stream>>>(vecA);

  int gmax = (E > N ? E : N);
  build_adj<<<(gmax + 255) / 256, 256, 0, stream>>>(ei, E, adjmask, deg);
  scan_deg<<<1, 1024, 0, stream>>>(deg, offs, cursor);
  scatter_edges<<<(E + 255) / 256, 256, 0, stream>>>(ei, E, cursor, neigh);

  for (int it = 0; it < SK_ITERS; ++it) {
    sk_pass<<<N, 256, 0, stream>>>(logits, vecA, vecB, lse, it == 0 ? 1 : 0);
    sk_pass<<<N, 256, 0, stream>>>(logits, vecB, vecA, lse, 0);
  }
  loss1_pass<<<N, 256, 0, stream>>>(logits, vecB, vecA, lse, term1);

  adj2_kernel<<<N, 128, 0, stream>>>(adjmask, offs, deg, neigh, adj2, colcount);
  loss2_kernel<<<N, 128, 0, stream>>>(adj2, colcount, logits, lse, term2);

  final_reduce<<<1, 256, 0, stream>>>(term1, term2, outp);
}

// Round 6
// 385.809 us; speedup vs baseline: 1.5189x; 1.1955x over previous
//
#include <hip/hip_runtime.h>
#include <cstdint>
#include <cstddef>

#define N 4096
#define D 300
#define KP 320          // K padded to multiple of 32 for MFMA
#define INV_T 20.0f
#define SK_ITERS 10
#define NTILE 528       // 32*33/2 upper-triangle 128x128 tiles

typedef __attribute__((ext_vector_type(8))) short bf16x8;
typedef __attribute__((ext_vector_type(4))) float f32x4;
typedef __attribute__((ext_vector_type(8))) unsigned short ushort8;

// XCD-chunked swizzle: 528 = 8 * 66; block b -> tile (b&7)*66 + (b>>3).
// Same mapping in logits_mfma and the tile passes so each tile's data stays
// in one XCD's L2 across all 21 passes.
__device__ inline void tile_decode(int blk, int& bi, int& bj) {
  int lin = (blk & 7) * 66 + (blk >> 3);
  int a = 0;
  while (lin >= 32 - a) { lin -= 32 - a; ++a; }
  bi = a; bj = a + lin;
}

// ---------------- generic zero-fill ----------------
__global__ void zero_u32(unsigned int* __restrict__ p, int n) {
  int i = blockIdx.x * 256 + threadIdx.x;
  int stride = gridDim.x * 256;
  for (; i < n; i += stride) p[i] = 0u;
}

// ---------------- MLP GEMM: C = act(A @ B + bias), 4 rows/block ----------------
__global__ __launch_bounds__(320) void mlp_gemm(const float* __restrict__ A,
                                                const float* __restrict__ B,
                                                const float* __restrict__ bias,
                                                float* __restrict__ C, int relu) {
  __shared__ __align__(16) float As[4][304];
  int r0 = blockIdx.x * 4;
  for (int idx = threadIdx.x; idx < 4 * 300; idx += 320) {
    int r = idx / 300, k = idx - r * 300;
    As[r][k] = A[(size_t)(r0 + r) * D + k];
  }
  __syncthreads();
  int c = threadIdx.x;
  if (c < D) {
    float acc[4] = {0, 0, 0, 0};
    for (int k = 0; k < D; k += 4) {
      float b0 = B[(size_t)(k + 0) * D + c];
      float b1 = B[(size_t)(k + 1) * D + c];
      float b2 = B[(size_t)(k + 2) * D + c];
      float b3 = B[(size_t)(k + 3) * D + c];
#pragma unroll
      for (int r = 0; r < 4; ++r) {
        const float4 a4 = *reinterpret_cast<const float4*>(&As[r][k]);
        acc[r] += a4.x * b0 + a4.y * b1 + a4.z * b2 + a4.w * b3;
      }
    }
#pragma unroll
    for (int r = 0; r < 4; ++r) {
      float o = acc[r] + bias[c];
      if (relu) o = fmaxf(o, 0.0f);
      C[(size_t)(r0 + r) * D + c] = o;
    }
  }
}

// ------- row L2 normalize + split into bf16 hi/lo (K padded to 320 with zeros) -------
__device__ inline unsigned short bf16_rne(float v) {
  unsigned int u = __float_as_uint(v);
  unsigned int r = u + 0x7fffu + ((u >> 16) & 1u);
  return (unsigned short)(r >> 16);
}

__global__ __launch_bounds__(64) void normalize_split(const float* __restrict__ in,
                                                      unsigned short* __restrict__ fhi,
                                                      unsigned short* __restrict__ flo) {
  int row = blockIdx.x;
  const float* r = in + (size_t)row * D;
  float ss = 0.0f;
  for (int c = threadIdx.x; c < D; c += 64) {
    float v = r[c];
    ss += v * v;
  }
  for (int o = 32; o > 0; o >>= 1) ss += __shfl_down(ss, o);
  ss = __shfl(ss, 0);
  float inv = 1.0f / fmaxf(sqrtf(ss), 1e-12f);
  for (int c = threadIdx.x; c < KP; c += 64) {
    float v = (c < D) ? r[c] * inv : 0.0f;
    unsigned short h = bf16_rne(v);
    float hf = __uint_as_float((unsigned int)h << 16);
    unsigned short lo = bf16_rne(v - hf);
    fhi[(size_t)row * KP + c] = h;
    flo[(size_t)row * KP + c] = lo;
  }
}

// ------- logits = (f @ f^T) * INV_T via split-bf16 MFMA, UPPER-triangle tiles only ----
__global__ __launch_bounds__(256) void logits_mfma(const unsigned short* __restrict__ fhi,
                                                   const unsigned short* __restrict__ flo,
                                                   float* __restrict__ logits) {
  __shared__ unsigned short smem[4 * 128 * 32];  // Ahi | Alo | Bhi | Blo, each [128][32]
  int bi, bj;
  tile_decode(blockIdx.x, bi, bj);
  int row0 = bi * 128, col0 = bj * 128;
  int tid = threadIdx.x;
  int w = tid >> 6, l = tid & 63;
  int wr = w >> 1, wc = w & 1;
  f32x4 acc[4][4] = {};

  for (int k0 = 0; k0 < KP; k0 += 32) {
    ushort8 stg[8];
#pragma unroll
    for (int t = 0; t < 8; ++t) {
      int c = t * 256 + tid;
      int b = c >> 9, i = c & 511, row = i >> 2, k16 = i & 3;
      const unsigned short* base = (b & 1) ? flo : fhi;
      int blk = (b < 2) ? row0 : col0;
      stg[t] = *reinterpret_cast<const ushort8*>(
          &base[(size_t)(blk + row) * KP + k0 + k16 * 8]);
    }
    __syncthreads();
#pragma unroll
    for (int t = 0; t < 8; ++t) {
      int c = t * 256 + tid;
      *reinterpret_cast<ushort8*>(&smem[c * 8]) = stg[t];
    }
    __syncthreads();

    bf16x8 ah[4], al[4], bh[4], bl[4];
#pragma unroll
    for (int m = 0; m < 4; ++m) {
      int off = (wr * 64 + m * 16 + (l & 15)) * 32 + (l >> 4) * 8;
      ah[m] = *reinterpret_cast<const bf16x8*>(&smem[0 * 4096 + off]);
      al[m] = *reinterpret_cast<const bf16x8*>(&smem[1 * 4096 + off]);
    }
#pragma unroll
    for (int n = 0; n < 4; ++n) {
      int off = (wc * 64 + n * 16 + (l & 15)) * 32 + (l >> 4) * 8;
      bh[n] = *reinterpret_cast<const bf16x8*>(&smem[2 * 4096 + off]);
      bl[n] = *reinterpret_cast<const bf16x8*>(&smem[3 * 4096 + off]);
    }
#pragma unroll
    for (int m = 0; m < 4; ++m)
#pragma unroll
      for (int n = 0; n < 4; ++n) {
        acc[m][n] = __builtin_amdgcn_mfma_f32_16x16x32_bf16(ah[m], bh[n], acc[m][n], 0, 0, 0);
        acc[m][n] = __builtin_amdgcn_mfma_f32_16x16x32_bf16(ah[m], bl[n], acc[m][n], 0, 0, 0);
        acc[m][n] = __builtin_amdgcn_mfma_f32_16x16x32_bf16(al[m], bh[n], acc[m][n], 0, 0, 0);
      }
  }

  // epilogue: C/D layout col=lane&15, row=(lane>>4)*4+reg; store tile (no mirror)
  int rb = row0 + wr * 64, cb = col0 + wc * 64;
  int rsub = (l >> 4) * 4, csub = l & 15;
#pragma unroll
  for (int m = 0; m < 4; ++m) {
#pragma unroll
    for (int n = 0; n < 4; ++n) {
      int col = cb + n * 16 + csub;
#pragma unroll
      for (int j = 0; j < 4; ++j) {
        logits[(size_t)(rb + m * 16 + rsub + j) * N + col] = acc[m][n][j] * INV_T;
      }
    }
  }
}

// ---- symmetry-folded Sinkhorn half-step, stage 1: per-tile partial sums ----
// tile (bi,bj): rowpart_r = sum_c exp(l_rc) v[col0+c]  -> pr[bi*32+bj][r]
//               colpart_c = sum_r exp(l_rc) v[row0+r]  -> pr[bj*32+bi][c]  (bi!=bj)
__global__ __launch_bounds__(256) void sk_tile(const float* __restrict__ logits,
                                               const float* __restrict__ vin,
                                               float* __restrict__ pr) {
  __shared__ float red[16][8][17];
  int bi, bj;
  tile_decode(blockIdx.x, bi, bj);
  int row0 = bi * 128, col0 = bj * 128;
  int t = threadIdx.x, ty = t >> 4, tx = t & 15;
  int r0 = ty * 8, c0 = tx * 8;
  float vc[8];
  *reinterpret_cast<float4*>(&vc[0]) = *reinterpret_cast<const float4*>(&vin[col0 + c0]);
  *reinterpret_cast<float4*>(&vc[4]) = *reinterpret_cast<const float4*>(&vin[col0 + c0 + 4]);
  float cs[8] = {};
#pragma unroll
  for (int i = 0; i < 8; ++i) {
    const float* lp = logits + (size_t)(row0 + r0 + i) * N + col0 + c0;
    float4 q0 = *reinterpret_cast<const float4*>(lp);
    float4 q1 = *reinterpret_cast<const float4*>(lp + 4);
    float vri = vin[row0 + r0 + i];
    float e[8] = {__expf(q0.x), __expf(q0.y), __expf(q0.z), __expf(q0.w),
                  __expf(q1.x), __expf(q1.y), __expf(q1.z), __expf(q1.w)};
    float rs = 0.f;
#pragma unroll
    for (int j = 0; j < 8; ++j) { rs += e[j] * vc[j]; cs[j] += e[j] * vri; }
    red[ty][i][tx] = rs;
  }
  __syncthreads();
  if (t < 128) {
    float s = 0.f;
#pragma unroll
    for (int x = 0; x < 16; ++x) s += red[t >> 3][t & 7][x];
    pr[((size_t)bi * 32 + bj) * 128 + t] = s;
  }
  if (bi != bj) {
    __syncthreads();
#pragma unroll
    for (int j = 0; j < 8; ++j) red[tx][j][ty] = cs[j];
    __syncthreads();
    if (t < 128) {
      float s = 0.f;
#pragma unroll
      for (int y = 0; y < 16; ++y) s += red[t >> 3][t & 7][y];
      pr[((size_t)bj * 32 + bi) * 128 + t] = s;
    }
  }
}

// ---- stage 2: vout[i] = 1 / sum_s pr[blk(i)][s][i&127]; optional lse ----
__global__ __launch_bounds__(256) void sk_reduce(const float* __restrict__ pr,
                                                 float* __restrict__ vout,
                                                 float* __restrict__ lse, int store_lse) {
  int i = blockIdx.x * 256 + threadIdx.x;
  int a = i >> 7, ri = i & 127;
  float tot = 0.f;
#pragma unroll
  for (int s = 0; s < 32; ++s) tot += pr[((size_t)a * 32 + s) * 128 + ri];
  vout[i] = 1.0f / tot;
  if (store_lse) lse[i] = logf(tot);
}

// ---- folded loss1 stage 1: S0 = sum e*v, S1 = sum e*v*l (rows and cols) ----
__global__ __launch_bounds__(256) void loss1_tile(const float* __restrict__ logits,
                                                  const float* __restrict__ v,
                                                  float* __restrict__ pr0,
                                                  float* __restrict__ pr1) {
  __shared__ float red[16][8][17];
  int bi, bj;
  tile_decode(blockIdx.x, bi, bj);
  int row0 = bi * 128, col0 = bj * 128;
  int t = threadIdx.x, ty = t >> 4, tx = t & 15;
  int r0 = ty * 8, c0 = tx * 8;
  float vc[8];
  *reinterpret_cast<float4*>(&vc[0]) = *reinterpret_cast<const float4*>(&v[col0 + c0]);
  *reinterpret_cast<float4*>(&vc[4]) = *reinterpret_cast<const float4*>(&v[col0 + c0 + 4]);
  float cs0[8] = {}, cs1[8] = {};
  float rs0a[8], rs1a[8];
#pragma unroll
  for (int i = 0; i < 8; ++i) {
    const float* lp = logits + (size_t)(row0 + r0 + i) * N + col0 + c0;
    float4 q0 = *reinterpret_cast<const float4*>(lp);
    float4 q1 = *reinterpret_cast<const float4*>(lp + 4);
    float ql[8] = {q0.x, q0.y, q0.z, q0.w, q1.x, q1.y, q1.z, q1.w};
    float vri = v[row0 + r0 + i];
    float rs0 = 0.f, rs1 = 0.f;
#pragma unroll
    for (int j = 0; j < 8; ++j) {
      float l = ql[j];
      float e = __expf(l);
      float wv = e * vc[j];
      rs0 += wv; rs1 += wv * l;
      cs0[j] += e * vri; cs1[j] += e * vri * l;
    }
    rs0a[i] = rs0; rs1a[i] = rs1;
  }
  size_t up = ((size_t)bi * 32 + bj) * 128;
  size_t dn = ((size_t)bj * 32 + bi) * 128;
  // rows S0
#pragma unroll
  for (int i = 0; i < 8; ++i) red[ty][i][tx] = rs0a[i];
  __syncthreads();
  if (t < 128) {
    float s = 0.f;
#pragma unroll
    for (int x = 0; x < 16; ++x) s += red[t >> 3][t & 7][x];
    pr0[up + t] = s;
  }
  __syncthreads();
  // rows S1
#pragma unroll
  for (int i = 0; i < 8; ++i) red[ty][i][tx] = rs1a[i];
  __syncthreads();
  if (t < 128) {
    float s = 0.f;
#pragma unroll
    for (int x = 0; x < 16; ++x) s += red[t >> 3][t & 7][x];
    pr1[up + t] = s;
  }
  if (bi != bj) {
    __syncthreads();
#pragma unroll
    for (int j = 0; j < 8; ++j) red[tx][j][ty] = cs0[j];
    __syncthreads();
    if (t < 128) {
      float s = 0.f;
#pragma unroll
      for (int y = 0; y < 16; ++y) s += red[t >> 3][t & 7][y];
      pr0[dn + t] = s;
    }
    __syncthreads();
#pragma unroll
    for (int j = 0; j < 8; ++j) red[tx][j][ty] = cs1[j];
    __syncthreads();
    if (t < 128) {
      float s = 0.f;
#pragma unroll
      for (int y = 0; y < 16; ++y) s += red[t >> 3][t & 7][y];
      pr1[dn + t] = s;
    }
  }
}

// ---- loss1 stage 2: term1[i] = u_i * (S1_i - lse_i * S0_i) ----
__global__ __launch_bounds__(256) void loss1_reduce(const float* __restrict__ pr0,
                                                    const float* __restrict__ pr1,
                                                    const float* __restrict__ u,
                                                    const float* __restrict__ lse,
                                                    double* __restrict__ term1) {
  int i = blockIdx.x * 256 + threadIdx.x;
  int a = i >> 7, ri = i & 127;
  double s0 = 0.0, s1 = 0.0;
#pragma unroll
  for (int s = 0; s < 32; ++s) {
    s0 += (double)pr0[((size_t)a * 32 + s) * 128 + ri];
    s1 += (double)pr1[((size_t)a * 32 + s) * 128 + ri];
  }
  term1[i] = (double)u[i] * (s1 - (double)lse[i] * s0);
}

__global__ void init_ones(float* v) {
  int i = blockIdx.x * 256 + threadIdx.x;
  if (i < N) v[i] = 1.0f;
}

// ---------------- adjacency bitmask build + degree count (edge_index is int32) --------
__global__ void build_adj(const int* __restrict__ ei, int E,
                          unsigned int* __restrict__ adjmask, int* __restrict__ deg) {
  int t = blockIdx.x * 256 + threadIdx.x;
  if (t < E) {
    int s = ei[t] & (N - 1), d = ei[E + t] & (N - 1);
    atomicOr(&adjmask[(size_t)s * 128 + (d >> 5)], 1u << (d & 31));
    atomicAdd(&deg[s], 1);
  }
  if (t < N) atomicOr(&adjmask[(size_t)t * 128 + (t >> 5)], 1u << (t & 31));
}

// ---------------- exclusive scan of degrees (4096, single block) ----------------
__global__ __launch_bounds__(1024) void scan_deg(const int* __restrict__ deg,
                                                 int* __restrict__ offs,
                                                 int* __restrict__ cursor) {
  __shared__ int part[1024];
  int tid = threadIdx.x;
  int base = tid * 4;
  int l0 = deg[base + 0], l1 = deg[base + 1], l2 = deg[base + 2], l3 = deg[base + 3];
  part[tid] = l0 + l1 + l2 + l3;
  __syncthreads();
  for (int d = 1; d < 1024; d <<= 1) {
    int v = (tid >= d) ? part[tid - d] : 0;
    __syncthreads();
    part[tid] += v;
    __syncthreads();
  }
  int run = (tid > 0) ? part[tid - 1] : 0;
  offs[base + 0] = run; cursor[base + 0] = run; run += l0;
  offs[base + 1] = run; cursor[base + 1] = run; run += l1;
  offs[base + 2] = run; cursor[base + 2] = run; run += l2;
  offs[base + 3] = run; cursor[base + 3] = run;
}

__global__ void scatter_edges(const int* __restrict__ ei, int E,
                              int* __restrict__ cursor, int* __restrict__ neigh) {
  int t = blockIdx.x * 256 + threadIdx.x;
  if (t < E) {
    int s = ei[t] & (N - 1), d = ei[E + t] & (N - 1);
    int slot = atomicAdd(&cursor[s], 1);
    neigh[slot] = d;
  }
}

// ---------------- adj2 row = OR of adj rows {i} ∪ N(i); also column counts ----------
__global__ __launch_bounds__(128) void adj2_kernel(const unsigned int* __restrict__ adjmask,
                                                   const int* __restrict__ offs,
                                                   const int* __restrict__ deg,
                                                   const int* __restrict__ neigh,
                                                   unsigned int* __restrict__ adj2,
                                                   int* __restrict__ colcount) {
  int i = blockIdx.x, w = threadIdx.x;
  unsigned int acc = adjmask[(size_t)i * 128 + w];
  int o = offs[i], dg = deg[i];
  for (int n = 0; n < dg; ++n) {
    int k = neigh[o + n];
    acc |= adjmask[(size_t)k * 128 + w];
  }
  adj2[(size_t)i * 128 + w] = acc;
  unsigned int m = acc;
  while (m) {
    int b = __ffs(m) - 1;
    m &= m - 1;
    atomicAdd(&colcount[w * 32 + b], 1);
  }
}

// ------- loss2 row pass: term2[i] = sum_{j in adj2_i} (l_ij - lse_i)/colcount_j -------
// logits holds only the upper triangle -> fold (i,j) to (min,max)
__global__ __launch_bounds__(128) void loss2_kernel(const unsigned int* __restrict__ adj2,
                                                    const int* __restrict__ colcount,
                                                    const float* __restrict__ logits,
                                                    const float* __restrict__ lse,
                                                    double* __restrict__ term2) {
  __shared__ float sb[2], sb2[2];
  int i = blockIdx.x, w = threadIdx.x;
  unsigned int m = adj2[(size_t)i * 128 + w];
  float s = 0.0f, sc = 0.0f;
  while (m) {
    int b = __ffs(m) - 1;
    m &= m - 1;
    int j = w * 32 + b;
    float lij = (j < i) ? logits[(size_t)j * N + i] : logits[(size_t)i * N + j];
    float ic = 1.0f / (float)colcount[j];
    s += ic * lij;
    sc += ic;
  }
  for (int o = 32; o > 0; o >>= 1) {
    s += __shfl_down(s, o);
    sc += __shfl_down(sc, o);
  }
  int lane = w & 63, wid = w >> 6;
  if (lane == 0) { sb[wid] = s; sb2[wid] = sc; }
  __syncthreads();
  if (w == 0)
    term2[i] = (double)(sb[0] + sb[1]) - (double)lse[i] * (double)(sb2[0] + sb2[1]);
}

// ---------------- final: loss = -(sum term1 + sum term2) / N ----------------
__global__ __launch_bounds__(256) void final_reduce(const double* __restrict__ term1,
                                                    const double* __restrict__ term2,
                                                    float* __restrict__ out) {
  __shared__ double sb[4];
  double s = 0.0;
  for (int i = threadIdx.x; i < N; i += 256) s += term1[i] + term2[i];
  for (int o = 32; o > 0; o >>= 1) s += __shfl_down(s, o);
  int lane = threadIdx.x & 63, wid = threadIdx.x >> 6;
  if (lane == 0) sb[wid] = s;
  __syncthreads();
  if (threadIdx.x == 0) out[0] = (float)(-(sb[0] + sb[1] + sb[2] + sb[3]) / (double)N);
}

extern "C" void kernel_launch(void* const* d_in, const int* in_sizes, int n_in,
                              void* d_out, int out_size, void* d_ws, size_t ws_size,
                              hipStream_t stream) {
  const float* x  = (const float*)d_in[0];
  const float* W1 = (const float*)d_in[1];
  const float* b1 = (const float*)d_in[2];
  const float* W2 = (const float*)d_in[3];
  const float* b2 = (const float*)d_in[4];
  const int* ei = (const int*)d_in[5];
  int E = in_sizes[5] / 2;
  float* outp = (float*)d_out;

  char* w = (char*)d_ws;
  float* logits = (float*)w;  w += (size_t)N * N * 4;
  float* h      = (float*)w;  w += (size_t)N * D * 4;
  float* o2     = (float*)w;  w += (size_t)N * D * 4;
  unsigned short* fhi = (unsigned short*)w; w += (size_t)N * KP * 2;
  unsigned short* flo = (unsigned short*)w; w += (size_t)N * KP * 2;
  float* vecA   = (float*)w;  w += 16384;
  float* vecB   = (float*)w;  w += 16384;
  float* lse    = (float*)w;  w += 16384;
  double* term1 = (double*)w; w += 32768;
  double* term2 = (double*)w; w += 32768;
  float* pr0    = (float*)w;  w += 32 * 32 * 128 * 4;
  float* pr1    = (float*)w;  w += 32 * 32 * 128 * 4;
  // contiguous zero-init region: adjmask | colcount | deg
  unsigned int* adjmask = (unsigned int*)w; w += (size_t)N * 128 * 4;
  int* colcount = (int*)w;    w += 16384;
  int* deg      = (int*)w;    w += 16384;
  int zcount = N * 128 + 4096 + 4096;
  unsigned int* adj2 = (unsigned int*)w; w += (size_t)N * 128 * 4;
  int* offs   = (int*)w;      w += 16384;
  int* cursor = (int*)w;      w += 16384;
  int* neigh  = (int*)w;      w += (size_t)E * 4;

  zero_u32<<<512, 256, 0, stream>>>(adjmask, zcount);

  mlp_gemm<<<N / 4, 320, 0, stream>>>(x, W1, b1, h, 1);
  mlp_gemm<<<N / 4, 320, 0, stream>>>(h, W2, b2, o2, 0);
  normalize_split<<<N, 64, 0, stream>>>(o2, fhi, flo);
  logits_mfma<<<NTILE, 256, 0, stream>>>(fhi, flo, logits);
  init_ones<<<(N + 255) / 256, 256, 0, stream>>>(vecA);

  int gmax = (E > N ? E : N);
  build_adj<<<(gmax + 255) / 256, 256, 0, stream>>>(ei, E, adjmask, deg);
  scan_deg<<<1, 1024, 0, stream>>>(deg, offs, cursor);
  scatter_edges<<<(E + 255) / 256, 256, 0, stream>>>(ei, E, cursor, neigh);

  for (int it = 0; it < SK_ITERS; ++it) {
    sk_tile<<<NTILE, 256, 0, stream>>>(logits, vecA, pr0);
    sk_reduce<<<N / 256, 256, 0, stream>>>(pr0, vecB, lse, it == 0 ? 1 : 0);
    sk_tile<<<NTILE, 256, 0, stream>>>(logits, vecB, pr0);
    sk_reduce<<<N / 256, 256, 0, stream>>>(pr0, vecA, lse, 0);
  }
  loss1_tile<<<NTILE, 256, 0, stream>>>(logits, vecA, pr0, pr1);
  loss1_reduce<<<N / 256, 256, 0, stream>>>(pr0, pr1, vecB, lse, term1);

  adj2_kernel<<<N, 128, 0, stream>>>(adjmask, offs, deg, neigh, adj2, colcount);
  loss2_kernel<<<N, 128, 0, stream>>>(adj2, colcount, logits, lse, term2);

  final_reduce<<<1, 256, 0, stream>>>(term1, term2, outp);
}

// Round 8
// 320.554 us; speedup vs baseline: 1.8281x; 1.2036x over previous
//
#include <hip/hip_runtime.h>
#include <cstdint>
#include <cstddef>

#define N 4096
#define D 300
#define KP 320          // K padded to multiple of 32 for MFMA
#define INV_T 20.0f
#define SK_ITERS 10
#define NTILE 528       // 32*33/2 upper-triangle 128x128 tiles

typedef __attribute__((ext_vector_type(8))) short bf16x8;
typedef __attribute__((ext_vector_type(4))) float f32x4;
typedef __attribute__((ext_vector_type(8))) unsigned short ushort8;

// XCD-chunked swizzle: 528 = 8 * 66; block b -> tile (b&7)*66 + (b>>3).
// Same mapping in logits_mfma and all tile passes so each tile's K data stays
// in one XCD's L2 across all 21 passes.
__device__ inline void tile_decode(int blk, int& bi, int& bj) {
  int lin = (blk & 7) * 66 + (blk >> 3);
  int a = 0;
  while (lin >= 32 - a) { lin -= 32 - a; ++a; }
  bi = a; bj = a + lin;
}

// ---------------- generic zero-fill ----------------
__global__ void zero_u32(unsigned int* __restrict__ p, int n) {
  int i = blockIdx.x * 256 + threadIdx.x;
  int stride = gridDim.x * 256;
  for (; i < n; i += stride) p[i] = 0u;
}

// ---------------- MLP GEMM: C = act(A @ B + bias), 4 rows/block ----------------
__global__ __launch_bounds__(320) void mlp_gemm(const float* __restrict__ A,
                                                const float* __restrict__ B,
                                                const float* __restrict__ bias,
                                                float* __restrict__ C, int relu) {
  __shared__ __align__(16) float As[4][304];
  int r0 = blockIdx.x * 4;
  for (int idx = threadIdx.x; idx < 4 * 300; idx += 320) {
    int r = idx / 300, k = idx - r * 300;
    As[r][k] = A[(size_t)(r0 + r) * D + k];
  }
  __syncthreads();
  int c = threadIdx.x;
  if (c < D) {
    float acc[4] = {0, 0, 0, 0};
    for (int k = 0; k < D; k += 4) {
      float b0 = B[(size_t)(k + 0) * D + c];
      float b1 = B[(size_t)(k + 1) * D + c];
      float b2 = B[(size_t)(k + 2) * D + c];
      float b3 = B[(size_t)(k + 3) * D + c];
#pragma unroll
      for (int r = 0; r < 4; ++r) {
        const float4 a4 = *reinterpret_cast<const float4*>(&As[r][k]);
        acc[r] += a4.x * b0 + a4.y * b1 + a4.z * b2 + a4.w * b3;
      }
    }
#pragma unroll
    for (int r = 0; r < 4; ++r) {
      float o = acc[r] + bias[c];
      if (relu) o = fmaxf(o, 0.0f);
      C[(size_t)(r0 + r) * D + c] = o;
    }
  }
}

// ------- row L2 normalize + split into bf16 hi/lo (K padded to 320 with zeros) -------
__device__ inline unsigned short bf16_rne(float v) {
  unsigned int u = __float_as_uint(v);
  unsigned int r = u + 0x7fffu + ((u >> 16) & 1u);
  return (unsigned short)(r >> 16);
}

__global__ __launch_bounds__(64) void normalize_split(const float* __restrict__ in,
                                                      unsigned short* __restrict__ fhi,
                                                      unsigned short* __restrict__ flo) {
  int row = blockIdx.x;
  const float* r = in + (size_t)row * D;
  float ss = 0.0f;
  for (int c = threadIdx.x; c < D; c += 64) {
    float v = r[c];
    ss += v * v;
  }
  for (int o = 32; o > 0; o >>= 1) ss += __shfl_down(ss, o);
  ss = __shfl(ss, 0);
  float inv = 1.0f / fmaxf(sqrtf(ss), 1e-12f);
  for (int c = threadIdx.x; c < KP; c += 64) {
    float v = (c < D) ? r[c] * inv : 0.0f;
    unsigned short h = bf16_rne(v);
    float hf = __uint_as_float((unsigned int)h << 16);
    unsigned short lo = bf16_rne(v - hf);
    fhi[(size_t)row * KP + c] = h;
    flo[(size_t)row * KP + c] = lo;
  }
}

// ------- logits = (f @ f^T) * INV_T via split-bf16 MFMA, UPPER-triangle tiles only ----
// Also emits kexp = bf16(exp(logits)) for the Sinkhorn passes.
__global__ __launch_bounds__(256) void logits_mfma(const unsigned short* __restrict__ fhi,
                                                   const unsigned short* __restrict__ flo,
                                                   float* __restrict__ logits,
                                                   unsigned short* __restrict__ kexp) {
  __shared__ unsigned short smem[4 * 128 * 32];  // Ahi | Alo | Bhi | Blo, each [128][32]
  int bi, bj;
  tile_decode(blockIdx.x, bi, bj);
  int row0 = bi * 128, col0 = bj * 128;
  int tid = threadIdx.x;
  int w = tid >> 6, l = tid & 63;
  int wr = w >> 1, wc = w & 1;
  f32x4 acc[4][4] = {};

  for (int k0 = 0; k0 < KP; k0 += 32) {
    ushort8 stg[8];
#pragma unroll
    for (int t = 0; t < 8; ++t) {
      int c = t * 256 + tid;
      int b = c >> 9, i = c & 511, row = i >> 2, k16 = i & 3;
      const unsigned short* base = (b & 1) ? flo : fhi;
      int blk = (b < 2) ? row0 : col0;
      stg[t] = *reinterpret_cast<const ushort8*>(
          &base[(size_t)(blk + row) * KP + k0 + k16 * 8]);
    }
    __syncthreads();
#pragma unroll
    for (int t = 0; t < 8; ++t) {
      int c = t * 256 + tid;
      *reinterpret_cast<ushort8*>(&smem[c * 8]) = stg[t];
    }
    __syncthreads();

    bf16x8 ah[4], al[4], bh[4], bl[4];
#pragma unroll
    for (int m = 0; m < 4; ++m) {
      int off = (wr * 64 + m * 16 + (l & 15)) * 32 + (l >> 4) * 8;
      ah[m] = *reinterpret_cast<const bf16x8*>(&smem[0 * 4096 + off]);
      al[m] = *reinterpret_cast<const bf16x8*>(&smem[1 * 4096 + off]);
    }
#pragma unroll
    for (int n = 0; n < 4; ++n) {
      int off = (wc * 64 + n * 16 + (l & 15)) * 32 + (l >> 4) * 8;
      bh[n] = *reinterpret_cast<const bf16x8*>(&smem[2 * 4096 + off]);
      bl[n] = *reinterpret_cast<const bf16x8*>(&smem[3 * 4096 + off]);
    }
#pragma unroll
    for (int m = 0; m < 4; ++m)
#pragma unroll
      for (int n = 0; n < 4; ++n) {
        acc[m][n] = __builtin_amdgcn_mfma_f32_16x16x32_bf16(ah[m], bh[n], acc[m][n], 0, 0, 0);
        acc[m][n] = __builtin_amdgcn_mfma_f32_16x16x32_bf16(ah[m], bl[n], acc[m][n], 0, 0, 0);
        acc[m][n] = __builtin_amdgcn_mfma_f32_16x16x32_bf16(al[m], bh[n], acc[m][n], 0, 0, 0);
      }
  }

  // epilogue: C/D layout col=lane&15, row=(lane>>4)*4+reg; store tile (no mirror)
  int rb = row0 + wr * 64, cb = col0 + wc * 64;
  int rsub = (l >> 4) * 4, csub = l & 15;
#pragma unroll
  for (int m = 0; m < 4; ++m) {
#pragma unroll
    for (int n = 0; n < 4; ++n) {
      int col = cb + n * 16 + csub;
#pragma unroll
      for (int j = 0; j < 4; ++j) {
        size_t idx = (size_t)(rb + m * 16 + rsub + j) * N + col;
        float lv = acc[m][n][j] * INV_T;
        logits[idx] = lv;
        kexp[idx] = bf16_rne(__expf(lv));
      }
    }
  }
}

// ---- fused symmetry-folded Sinkhorn half-step over bf16 K ----
// Reads totprev (row sums of previous half-step; ones if first), atomically
// accumulates this half-step's row/col partials into totcur, zeros totnext.
// Pass 1's diagonal blocks also write lse = log(pass-0 row sums).
__global__ __launch_bounds__(256) void sk_fused(const unsigned short* __restrict__ kexp,
                                                const float* __restrict__ totprev,
                                                float* __restrict__ totcur,
                                                float* __restrict__ totnext,
                                                float* __restrict__ lse,
                                                int first, int write_lse) {
  __shared__ float red[16][8][17];
  __shared__ float vrow[128], vcol[128];
  int bi, bj;
  tile_decode(blockIdx.x, bi, bj);
  int row0 = bi * 128, col0 = bj * 128;
  int t = threadIdx.x;
  // zero next-pass accumulator (528 blocks x 8 covers 4096)
  if (t < 8) {
    int zb = blockIdx.x * 8 + t;
    if (zb < N) totnext[zb] = 0.f;
  }
  if (first) {
    if (t < 128) vrow[t] = 1.f;
    else vcol[t - 128] = 1.f;
  } else {
    if (t < 128) {
      float tt = totprev[row0 + t];
      vrow[t] = 1.f / tt;
      if (write_lse && bi == bj) lse[row0 + t] = logf(tt);
    } else {
      vcol[t - 128] = 1.f / totprev[col0 + (t - 128)];
    }
  }
  __syncthreads();
  int ty = t >> 4, tx = t & 15;
  int r0 = ty * 8, c0 = tx * 8;
  float vc[8];
#pragma unroll
  for (int j = 0; j < 8; ++j) vc[j] = vcol[c0 + j];
  float cs[8] = {};
  float rsa[8];
#pragma unroll
  for (int i = 0; i < 8; ++i) {
    const ushort8 kv = *reinterpret_cast<const ushort8*>(
        &kexp[(size_t)(row0 + r0 + i) * N + col0 + c0]);
    float vri = vrow[r0 + i];
    float rs = 0.f;
#pragma unroll
    for (int j = 0; j < 8; ++j) {
      float e = __uint_as_float((unsigned int)(unsigned short)kv[j] << 16);
      rs += e * vc[j];
      cs[j] += e * vri;
    }
    rsa[i] = rs;
  }
#pragma unroll
  for (int i = 0; i < 8; ++i) red[ty][i][tx] = rsa[i];
  __syncthreads();
  if (t < 128) {
    float s = 0.f;
#pragma unroll
    for (int x = 0; x < 16; ++x) s += red[t >> 3][t & 7][x];
    atomicAdd(&totcur[row0 + t], s);
  }
  if (bi != bj) {
    __syncthreads();
#pragma unroll
    for (int j = 0; j < 8; ++j) red[tx][j][ty] = cs[j];
    __syncthreads();
    if (t < 128) {
      float s = 0.f;
#pragma unroll
      for (int y = 0; y < 16; ++y) s += red[t >> 3][t & 7][y];
      atomicAdd(&totcur[col0 + t], s);
    }
  }
}

// ---- u = 1/a, v = 1/b (final Sinkhorn scalings) ----
__global__ void invert2(const float* __restrict__ a, const float* __restrict__ b,
                        float* __restrict__ ua, float* __restrict__ vb) {
  int i = blockIdx.x * 256 + threadIdx.x;
  ua[i] = 1.f / a[i];
  vb[i] = 1.f / b[i];
}

// ---- folded loss1 stage 1: S0 = sum e*v, S1 = sum e*v*l (rows and cols), f32 ----
__global__ __launch_bounds__(256) void loss1_tile(const float* __restrict__ logits,
                                                  const float* __restrict__ v,
                                                  float* __restrict__ pr0,
                                                  float* __restrict__ pr1) {
  __shared__ float red[16][8][17];
  int bi, bj;
  tile_decode(blockIdx.x, bi, bj);
  int row0 = bi * 128, col0 = bj * 128;
  int t = threadIdx.x, ty = t >> 4, tx = t & 15;
  int r0 = ty * 8, c0 = tx * 8;
  float vc[8];
  *reinterpret_cast<float4*>(&vc[0]) = *reinterpret_cast<const float4*>(&v[col0 + c0]);
  *reinterpret_cast<float4*>(&vc[4]) = *reinterpret_cast<const float4*>(&v[col0 + c0 + 4]);
  float cs0[8] = {}, cs1[8] = {};
  float rs0a[8], rs1a[8];
#pragma unroll
  for (int i = 0; i < 8; ++i) {
    const float* lp = logits + (size_t)(row0 + r0 + i) * N + col0 + c0;
    float4 q0 = *reinterpret_cast<const float4*>(lp);
    float4 q1 = *reinterpret_cast<const float4*>(lp + 4);
    float ql[8] = {q0.x, q0.y, q0.z, q0.w, q1.x, q1.y, q1.z, q1.w};
    float vri = v[row0 + r0 + i];
    float rs0 = 0.f, rs1 = 0.f;
#pragma unroll
    for (int j = 0; j < 8; ++j) {
      float l = ql[j];
      float e = __expf(l);
      float wv = e * vc[j];
      rs0 += wv; rs1 += wv * l;
      cs0[j] += e * vri; cs1[j] += e * vri * l;
    }
    rs0a[i] = rs0; rs1a[i] = rs1;
  }
  size_t up = ((size_t)bi * 32 + bj) * 128;
  size_t dn = ((size_t)bj * 32 + bi) * 128;
#pragma unroll
  for (int i = 0; i < 8; ++i) red[ty][i][tx] = rs0a[i];
  __syncthreads();
  if (t < 128) {
    float s = 0.f;
#pragma unroll
    for (int x = 0; x < 16; ++x) s += red[t >> 3][t & 7][x];
    pr0[up + t] = s;
  }
  __syncthreads();
#pragma unroll
  for (int i = 0; i < 8; ++i) red[ty][i][tx] = rs1a[i];
  __syncthreads();
  if (t < 128) {
    float s = 0.f;
#pragma unroll
    for (int x = 0; x < 16; ++x) s += red[t >> 3][t & 7][x];
    pr1[up + t] = s;
  }
  if (bi != bj) {
    __syncthreads();
#pragma unroll
    for (int j = 0; j < 8; ++j) red[tx][j][ty] = cs0[j];
    __syncthreads();
    if (t < 128) {
      float s = 0.f;
#pragma unroll
      for (int y = 0; y < 16; ++y) s += red[t >> 3][t & 7][y];
      pr0[dn + t] = s;
    }
    __syncthreads();
#pragma unroll
    for (int j = 0; j < 8; ++j) red[tx][j][ty] = cs1[j];
    __syncthreads();
    if (t < 128) {
      float s = 0.f;
#pragma unroll
      for (int y = 0; y < 16; ++y) s += red[t >> 3][t & 7][y];
      pr1[dn + t] = s;
    }
  }
}

// ---- loss1 stage 2: term1[i] = u_i * (S1_i - lse_i * S0_i) ----
__global__ __launch_bounds__(256) void loss1_reduce(const float* __restrict__ pr0,
                                                    const float* __restrict__ pr1,
                                                    const float* __restrict__ u,
                                                    const float* __restrict__ lse,
                                                    double* __restrict__ term1) {
  int i = blockIdx.x * 256 + threadIdx.x;
  int a = i >> 7, ri = i & 127;
  double s0 = 0.0, s1 = 0.0;
#pragma unroll
  for (int s = 0; s < 32; ++s) {
    s0 += (double)pr0[((size_t)a * 32 + s) * 128 + ri];
    s1 += (double)pr1[((size_t)a * 32 + s) * 128 + ri];
  }
  term1[i] = (double)u[i] * (s1 - (double)lse[i] * s0);
}

// ---------------- adjacency bitmask build + degree count (edge_index is int32) --------
__global__ void build_adj(const int* __restrict__ ei, int E,
                          unsigned int* __restrict__ adjmask, int* __restrict__ deg) {
  int t = blockIdx.x * 256 + threadIdx.x;
  if (t < E) {
    int s = ei[t] & (N - 1), d = ei[E + t] & (N - 1);
    atomicOr(&adjmask[(size_t)s * 128 + (d >> 5)], 1u << (d & 31));
    atomicAdd(&deg[s], 1);
  }
  if (t < N) atomicOr(&adjmask[(size_t)t * 128 + (t >> 5)], 1u << (t & 31));
}

// ---------------- exclusive scan of degrees (4096, single block) ----------------
__global__ __launch_bounds__(1024) void scan_deg(const int* __restrict__ deg,
                                                 int* __restrict__ offs,
                                                 int* __restrict__ cursor) {
  __shared__ int part[1024];
  int tid = threadIdx.x;
  int base = tid * 4;
  int l0 = deg[base + 0], l1 = deg[base + 1], l2 = deg[base + 2], l3 = deg[base + 3];
  part[tid] = l0 + l1 + l2 + l3;
  __syncthreads();
  for (int d = 1; d < 1024; d <<= 1) {
    int v = (tid >= d) ? part[tid - d] : 0;
    __syncthreads();
    part[tid] += v;
    __syncthreads();
  }
  int run = (tid > 0) ? part[tid - 1] : 0;
  offs[base + 0] = run; cursor[base + 0] = run; run += l0;
  offs[base + 1] = run; cursor[base + 1] = run; run += l1;
  offs[base + 2] = run; cursor[base + 2] = run; run += l2;
  offs[base + 3] = run; cursor[base + 3] = run;
}

__global__ void scatter_edges(const int* __restrict__ ei, int E,
                              int* __restrict__ cursor, int* __restrict__ neigh) {
  int t = blockIdx.x * 256 + threadIdx.x;
  if (t < E) {
    int s = ei[t] & (N - 1), d = ei[E + t] & (N - 1);
    int slot = atomicAdd(&cursor[s], 1);
    neigh[slot] = d;
  }
}

// ---------------- adj2 row = OR of adj rows {i} ∪ N(i); also column counts ----------
__global__ __launch_bounds__(128) void adj2_kernel(const unsigned int* __restrict__ adjmask,
                                                   const int* __restrict__ offs,
                                                   const int* __restrict__ deg,
                                                   const int* __restrict__ neigh,
                                                   unsigned int* __restrict__ adj2,
                                                   int* __restrict__ colcount) {
  int i = blockIdx.x, w = threadIdx.x;
  unsigned int acc = adjmask[(size_t)i * 128 + w];
  int o = offs[i], dg = deg[i];
  for (int n = 0; n < dg; ++n) {
    int k = neigh[o + n];
    acc |= adjmask[(size_t)k * 128 + w];
  }
  adj2[(size_t)i * 128 + w] = acc;
  unsigned int m = acc;
  while (m) {
    int b = __ffs(m) - 1;
    m &= m - 1;
    atomicAdd(&colcount[w * 32 + b], 1);
  }
}

// ------- loss2 row pass: term2[i] = sum_{j in adj2_i} (l_ij - lse_i)/colcount_j -------
// logits holds only the upper triangle -> fold (i,j) to (min,max)
__global__ __launch_bounds__(128) void loss2_kernel(const unsigned int* __restrict__ adj2,
                                                    const int* __restrict__ colcount,
                                                    const float* __restrict__ logits,
                                                    const float* __restrict__ lse,
                                                    double* __restrict__ term2) {
  __shared__ float sb[2], sb2[2];
  int i = blockIdx.x, w = threadIdx.x;
  unsigned int m = adj2[(size_t)i * 128 + w];
  float s = 0.0f, sc = 0.0f;
  while (m) {
    int b = __ffs(m) - 1;
    m &= m - 1;
    int j = w * 32 + b;
    float lij = (j < i) ? logits[(size_t)j * N + i] : logits[(size_t)i * N + j];
    float ic = 1.0f / (float)colcount[j];
    s += ic * lij;
    sc += ic;
  }
  for (int o = 32; o > 0; o >>= 1) {
    s += __shfl_down(s, o);
    sc += __shfl_down(sc, o);
  }
  int lane = w & 63, wid = w >> 6;
  if (lane == 0) { sb[wid] = s; sb2[wid] = sc; }
  __syncthreads();
  if (w == 0)
    term2[i] = (double)(sb[0] + sb[1]) - (double)lse[i] * (double)(sb2[0] + sb2[1]);
}

// ---------------- final: loss = -(sum term1 + sum term2) / N ----------------
__global__ __launch_bounds__(256) void final_reduce(const double* __restrict__ term1,
                                                    const double* __restrict__ term2,
                                                    float* __restrict__ out) {
  __shared__ double sb[4];
  double s = 0.0;
  for (int i = threadIdx.x; i < N; i += 256) s += term1[i] + term2[i];
  for (int o = 32; o > 0; o >>= 1) s += __shfl_down(s, o);
  int lane = threadIdx.x & 63, wid = threadIdx.x >> 6;
  if (lane == 0) sb[wid] = s;
  __syncthreads();
  if (threadIdx.x == 0) out[0] = (float)(-(sb[0] + sb[1] + sb[2] + sb[3]) / (double)N);
}

extern "C" void kernel_launch(void* const* d_in, const int* in_sizes, int n_in,
                              void* d_out, int out_size, void* d_ws, size_t ws_size,
                              hipStream_t stream) {
  const float* x  = (const float*)d_in[0];
  const float* W1 = (const float*)d_in[1];
  const float* b1 = (const float*)d_in[2];
  const float* W2 = (const float*)d_in[3];
  const float* b2 = (const float*)d_in[4];
  const int* ei = (const int*)d_in[5];
  int E = in_sizes[5] / 2;
  float* outp = (float*)d_out;

  char* w = (char*)d_ws;
  float* logits = (float*)w;  w += (size_t)N * N * 4;
  unsigned short* kexp = (unsigned short*)w; w += (size_t)N * N * 2;
  float* h      = (float*)w;  w += (size_t)N * D * 4;
  float* o2     = (float*)w;  w += (size_t)N * D * 4;
  unsigned short* fhi = (unsigned short*)w; w += (size_t)N * KP * 2;
  unsigned short* flo = (unsigned short*)w; w += (size_t)N * KP * 2;
  float* vecA   = (float*)w;  w += 16384;
  float* vecB   = (float*)w;  w += 16384;
  float* lse    = (float*)w;  w += 16384;
  double* term1 = (double*)w; w += 32768;
  double* term2 = (double*)w; w += 32768;
  float* pr0    = (float*)w;  w += 32 * 32 * 128 * 4;
  float* pr1    = (float*)w;  w += 32 * 32 * 128 * 4;
  // contiguous zero-init region: sk tot bufs (3) | adjmask | colcount | deg
  float* sb0 = (float*)w;     w += 16384;
  float* sb1 = (float*)w;     w += 16384;
  float* sb2 = (float*)w;     w += 16384;
  unsigned int* adjmask = (unsigned int*)w; w += (size_t)N * 128 * 4;
  int* colcount = (int*)w;    w += 16384;
  int* deg      = (int*)w;    w += 16384;
  int zcount = 3 * N + N * 128 + 4096 + 4096;
  unsigned int* adj2 = (unsigned int*)w; w += (size_t)N * 128 * 4;
  int* offs   = (int*)w;      w += 16384;
  int* cursor = (int*)w;      w += 16384;
  int* neigh  = (int*)w;      w += (size_t)E * 4;

  zero_u32<<<512, 256, 0, stream>>>((unsigned int*)sb0, zcount);

  mlp_gemm<<<N / 4, 320, 0, stream>>>(x, W1, b1, h, 1);
  mlp_gemm<<<N / 4, 320, 0, stream>>>(h, W2, b2, o2, 0);
  normalize_split<<<N, 64, 0, stream>>>(o2, fhi, flo);
  logits_mfma<<<NTILE, 256, 0, stream>>>(fhi, flo, logits, kexp);

  int gmax = (E > N ? E : N);
  build_adj<<<(gmax + 255) / 256, 256, 0, stream>>>(ei, E, adjmask, deg);
  scan_deg<<<1, 1024, 0, stream>>>(deg, offs, cursor);
  scatter_edges<<<(E + 255) / 256, 256, 0, stream>>>(ei, E, cursor, neigh);

  // 20 fused Sinkhorn half-steps over bf16 K (3-buffer tot rotation).
  float* bufs[3] = {sb0, sb1, sb2};
  for (int p = 0; p < 2 * SK_ITERS; ++p) {
    sk_fused<<<NTILE, 256, 0, stream>>>(kexp,
        p == 0 ? sb0 : bufs[(p - 1) % 3],
        bufs[p % 3], bufs[(p + 1) % 3], lse,
        p == 0 ? 1 : 0, p == 1 ? 1 : 0);
  }
  // p=18 accumulated bufs[0] -> u = 1/bufs[0]; p=19 accumulated bufs[1] -> v = 1/bufs[1]
  invert2<<<N / 256, 256, 0, stream>>>(bufs[0], bufs[1], vecA, vecB);

  loss1_tile<<<NTILE, 256, 0, stream>>>(logits, vecA, pr0, pr1);
  loss1_reduce<<<N / 256, 256, 0, stream>>>(pr0, pr1, vecB, lse, term1);

  adj2_kernel<<<N, 128, 0, stream>>>(adjmask, offs, deg, neigh, adj2, colcount);
  loss2_kernel<<<N, 128, 0, stream>>>(adj2, colcount, logits, lse, term2);

  final_reduce<<<1, 256, 0, stream>>>(term1, term2, outp);
}